// Round 3
// baseline (240.137 us; speedup 1.0000x reference)
//
#include <hip/hip_runtime.h>

typedef __bf16 bf16;
typedef __bf16 bf16x4 __attribute__((ext_vector_type(4)));
typedef __bf16 bf16x8 __attribute__((ext_vector_type(8)));
typedef float  f32x4  __attribute__((ext_vector_type(4)));

#define MFMA16(a, b, c) __builtin_amdgcn_mfma_f32_16x16x32_bf16((a), (b), (c), 0, 0, 0)

static constexpr int Bn = 8, T = 2048, C = 1024, H = 128;
static constexpr int M = Bn * T; // 16384

// ---------------------------------------------------------------------------
// Kernel 0: transpose + hi/lo split  W[C][H] fp32 -> wt_hi/wt_lo [3][H][C] bf16
// ---------------------------------------------------------------------------
__global__ __launch_bounds__(256) void kwt(const float* __restrict__ Wq,
                                           const float* __restrict__ Wk,
                                           const float* __restrict__ Wv,
                                           bf16* __restrict__ wth,
                                           bf16* __restrict__ wtl) {
  __shared__ float tl[32][33];
  const int w = blockIdx.z;
  const float* src = (w == 0) ? Wq : (w == 1) ? Wk : Wv;
  bf16* dh = wth + (size_t)w * H * C;
  bf16* dl = wtl + (size_t)w * H * C;
  const int k0 = blockIdx.x * 32, n0 = blockIdx.y * 32;
  const int tx = threadIdx.x & 31, ty = threadIdx.x >> 5; // 32 x 8
  for (int i = ty; i < 32; i += 8) tl[i][tx] = src[(size_t)(k0 + i) * H + n0 + tx];
  __syncthreads();
  for (int i = ty; i < 32; i += 8) {
    float v = tl[tx][i];
    bf16 h = (bf16)v;
    bf16 l = (bf16)(v - (float)h);
    dh[(size_t)(n0 + i) * C + k0 + tx] = h;
    dl[(size_t)(n0 + i) * C + k0 + tx] = l;
  }
}

// ---------------------------------------------------------------------------
// Kernel 1: QKV projection, split-bf16 3-term (hh + lh + hl) for accuracy.
// grid (M/64, 3).  256 thr = 4 waves (2x2).  Tile 64m x 128n, BK=64.
// x fp32 -> split in-register while staging.  W pre-split by kwt.
// y==0 -> q hi/lo [t][h]; y==1 -> k hi/lo; y==2 -> v bf16 transposed [b][h][t].
// ---------------------------------------------------------------------------
__global__ __launch_bounds__(256) void proj_kernel(const float* __restrict__ x,
                                                   const bf16* __restrict__ wth,
                                                   const bf16* __restrict__ wtl,
                                                   bf16* __restrict__ qh, bf16* __restrict__ ql,
                                                   bf16* __restrict__ kh, bf16* __restrict__ kl,
                                                   bf16* __restrict__ vt) {
  __shared__ __align__(16) bf16 Ah[64 * 72], Al[64 * 72];    // [m][k] padded
  __shared__ __align__(16) bf16 Bh[128 * 72], Bl[128 * 72];  // [n][k] padded
  const int tid = threadIdx.x;
  const int lane = tid & 63, g = lane >> 4, r16 = lane & 15;
  const int wave = tid >> 6, wr = wave >> 1, wc = wave & 1;
  const int m0 = blockIdx.x * 64;
  const int which = blockIdx.y;
  const bf16* wh = wth + (size_t)which * H * C;
  const bf16* wl = wtl + (size_t)which * H * C;

  // A: 64x64 fp32 = 1024 float4 chunks; B: 128x64 bf16 = 1024 bf16x8 chunks/plane
  int am[4], ak[4], bn[4], bk[4];
#pragma unroll
  for (int it = 0; it < 4; ++it) {
    int c = it * 256 + tid;
    am[it] = c >> 4; ak[it] = (c & 15) << 2;
    bn[it] = c >> 3; bk[it] = (c & 7) << 3;
  }

  f32x4 ra[4]; bf16x8 rbh[4], rbl[4];
#pragma unroll
  for (int it = 0; it < 4; ++it) {
    ra[it]  = *(const f32x4*)&x[(size_t)(m0 + am[it]) * C + ak[it]];
    rbh[it] = *(const bf16x8*)&wh[(size_t)bn[it] * C + bk[it]];
    rbl[it] = *(const bf16x8*)&wl[(size_t)bn[it] * C + bk[it]];
  }

  f32x4 acc[2][4] = {};

  for (int k0 = 0; k0 < C; k0 += 64) {
    __syncthreads();
#pragma unroll
    for (int it = 0; it < 4; ++it) {
      bf16x4 hv, lv;
#pragma unroll
      for (int j = 0; j < 4; ++j) {
        float v = ra[it][j];
        bf16 h = (bf16)v;
        hv[j] = h;
        lv[j] = (bf16)(v - (float)h);
      }
      *(bf16x4*)&Ah[am[it] * 72 + ak[it]] = hv;
      *(bf16x4*)&Al[am[it] * 72 + ak[it]] = lv;
      *(bf16x8*)&Bh[bn[it] * 72 + bk[it]] = rbh[it];
      *(bf16x8*)&Bl[bn[it] * 72 + bk[it]] = rbl[it];
    }
    if (k0 + 64 < C) {
      const int kn = k0 + 64;
#pragma unroll
      for (int it = 0; it < 4; ++it) {
        ra[it]  = *(const f32x4*)&x[(size_t)(m0 + am[it]) * C + kn + ak[it]];
        rbh[it] = *(const bf16x8*)&wh[(size_t)bn[it] * C + kn + bk[it]];
        rbl[it] = *(const bf16x8*)&wl[(size_t)bn[it] * C + kn + bk[it]];
      }
    }
    __syncthreads();
#pragma unroll
    for (int kb = 0; kb < 2; ++kb) {
      bf16x8 afh[2], afl[2], bfh[4], bfl[4];
#pragma unroll
      for (int mt = 0; mt < 2; ++mt) {
        const int ro = (wr * 32 + mt * 16 + r16) * 72 + kb * 32 + g * 8;
        afh[mt] = *(const bf16x8*)&Ah[ro];
        afl[mt] = *(const bf16x8*)&Al[ro];
      }
#pragma unroll
      for (int nt = 0; nt < 4; ++nt) {
        const int ro = (wc * 64 + nt * 16 + r16) * 72 + kb * 32 + g * 8;
        bfh[nt] = *(const bf16x8*)&Bh[ro];
        bfl[nt] = *(const bf16x8*)&Bl[ro];
      }
#pragma unroll
      for (int mt = 0; mt < 2; ++mt)
#pragma unroll
        for (int nt = 0; nt < 4; ++nt) {
          acc[mt][nt] = MFMA16(afh[mt], bfh[nt], acc[mt][nt]);
          acc[mt][nt] = MFMA16(afl[mt], bfh[nt], acc[mt][nt]);
          acc[mt][nt] = MFMA16(afh[mt], bfl[nt], acc[mt][nt]);
        }
    }
  }

  // epilogue.  C/D frag: col = lane&15, row = (lane>>4)*4 + reg  [m89]
  if (which < 2) {
    bf16* dh = which ? kh : qh;
    bf16* dl = which ? kl : ql;
#pragma unroll
    for (int mt = 0; mt < 2; ++mt)
#pragma unroll
      for (int nt = 0; nt < 4; ++nt) {
        const int mb = m0 + wr * 32 + mt * 16 + g * 4;
        const int col = wc * 64 + nt * 16 + r16;
#pragma unroll
        for (int r = 0; r < 4; ++r) {
          float v = acc[mt][nt][r];
          bf16 h = (bf16)v;
          dh[(size_t)(mb + r) * H + col] = h;
          dl[(size_t)(mb + r) * H + col] = (bf16)(v - (float)h);
        }
      }
  } else {
    const int b = m0 >> 11;
    const int tb0 = m0 & 2047;
    bf16* vbase = vt + (size_t)b * H * T;
#pragma unroll
    for (int mt = 0; mt < 2; ++mt)
#pragma unroll
      for (int nt = 0; nt < 4; ++nt) {
        const int tib = tb0 + wr * 32 + mt * 16 + g * 4;
        const int h = wc * 64 + nt * 16 + r16;
        bf16x4 pk;
#pragma unroll
        for (int r = 0; r < 4; ++r) pk[r] = (bf16)acc[mt][nt][r];
        *(bf16x4*)&vbase[(size_t)h * T + tib] = pk;
      }
  }
}

// ---------------------------------------------------------------------------
// Kernel 2: causal flash attention, no scale.  Split-bf16 QK^T (3-term).
// 1024 wave-tasks (batch x 16 q rows); block = 4 waves; grid 256, balanced:
// wave0 t=2b, wave1 t=2b+1, wave2 t=1022-2b, wave3 t=1023-2b (qg-sum const).
// Swapped QK^T (mfma(K,Q)): lane owns one q row -> shuffle softmax.
// PV: A = V^T [b][h][t], B = P^T via per-wave LDS round-trip -> out^T.
// OUTPUT IS FP32 (reference output dtype is float32).
// ---------------------------------------------------------------------------
__global__ __launch_bounds__(256) void attn_kernel(const bf16* __restrict__ qhp,
                                                   const bf16* __restrict__ qlp,
                                                   const bf16* __restrict__ khp,
                                                   const bf16* __restrict__ klp,
                                                   const bf16* __restrict__ vp,
                                                   float* __restrict__ out) {
  __shared__ __align__(16) bf16 Pl[4][16][72]; // per-wave P [q][s] padded
  const int tid = threadIdx.x, lane = tid & 63, wave = tid >> 6;
  const int g = lane >> 4, q15 = lane & 15;
  const int bb = blockIdx.x;
  int t;
  if (wave == 0) t = 2 * bb;
  else if (wave == 1) t = 2 * bb + 1;
  else if (wave == 2) t = 1022 - 2 * bb;
  else t = 1023 - 2 * bb;
  const int batch = t >> 7, qg = t & 127;
  const int q0 = qg * 16;
  const bf16* qbh = qhp + (size_t)batch * T * H;
  const bf16* qbl = qlp + (size_t)batch * T * H;
  const bf16* kbh = khp + (size_t)batch * T * H;
  const bf16* kbl = klp + (size_t)batch * T * H;
  const bf16* vb  = vp  + (size_t)batch * H * T;
  float* ob = out + (size_t)batch * T * H;

  // Q B-frags, hoisted: col = q (lane&15), k = h contiguous
  bf16x8 qfh[4], qfl[4];
#pragma unroll
  for (int k4 = 0; k4 < 4; ++k4) {
    qfh[k4] = *(const bf16x8*)&qbh[(size_t)(q0 + q15) * H + k4 * 32 + g * 8];
    qfl[k4] = *(const bf16x8*)&qbl[(size_t)(q0 + q15) * H + k4 * 32 + g * 8];
  }

  f32x4 o[8] = {};
  float mrun = -1e30f, lrun = 0.f;
  const int send = ((qg >> 2) + 1) * 64;

  for (int s0 = 0; s0 < send; s0 += 64) {
    const bool lastt = (s0 + 64 == send);
    // S^T[s][q]: A = K rows (row = s, k = h), B = Q.  3-term split product.
    f32x4 sacc[4] = {};
#pragma unroll
    for (int mt = 0; mt < 4; ++mt) {
#pragma unroll
      for (int k4 = 0; k4 < 4; ++k4) {
        const size_t ro = (size_t)(s0 + mt * 16 + q15) * H + k4 * 32 + g * 8;
        bf16x8 kfh = *(const bf16x8*)&kbh[ro];
        bf16x8 kfl = *(const bf16x8*)&kbl[ro];
        sacc[mt] = MFMA16(kfh, qfh[k4], sacc[mt]);
        sacc[mt] = MFMA16(kfl, qfh[k4], sacc[mt]);
        sacc[mt] = MFMA16(kfh, qfl[k4], sacc[mt]);
      }
    }
    if (lastt) {
#pragma unroll
      for (int mt = 0; mt < 4; ++mt)
#pragma unroll
        for (int r = 0; r < 4; ++r)
          if (s0 + mt * 16 + g * 4 + r > q0 + q15) sacc[mt][r] = -1e30f;
    }
    // online softmax: lane holds 16 s-values of ONE q row (via shfl 16/32)
    float tmax = -1e30f;
#pragma unroll
    for (int mt = 0; mt < 4; ++mt)
#pragma unroll
      for (int r = 0; r < 4; ++r) tmax = fmaxf(tmax, sacc[mt][r]);
    tmax = fmaxf(tmax, __shfl_xor(tmax, 16));
    tmax = fmaxf(tmax, __shfl_xor(tmax, 32));
    const float mnew = fmaxf(mrun, tmax);
    const float alpha = __expf(mrun - mnew);
    float lt = 0.f;
#pragma unroll
    for (int mt = 0; mt < 4; ++mt) {
      bf16x4 pk;
#pragma unroll
      for (int r = 0; r < 4; ++r) {
        const float p = __expf(sacc[mt][r] - mnew);
        lt += p;
        pk[r] = (bf16)p;
      }
      *(bf16x4*)&Pl[wave][q15][mt * 16 + g * 4] = pk; // own-wave slice
    }
    lt += __shfl_xor(lt, 16);
    lt += __shfl_xor(lt, 32);
    lrun = lrun * alpha + lt;
    mrun = mnew;
#pragma unroll
    for (int i = 0; i < 8; ++i) o[i] *= alpha;
    // P^T B-frags: col = q, k = s contiguous
    const bf16x8 pf0 = *(const bf16x8*)&Pl[wave][q15][g * 8];
    const bf16x8 pf1 = *(const bf16x8*)&Pl[wave][q15][32 + g * 8];
    // out^T += V^T * P^T  (A = V^T rows: row = h, k = s contiguous)
#pragma unroll
    for (int mt = 0; mt < 8; ++mt) {
      const bf16x8 vf0 = *(const bf16x8*)&vb[(size_t)(mt * 16 + q15) * T + s0 + g * 8];
      o[mt] = MFMA16(vf0, pf0, o[mt]);
      const bf16x8 vf1 = *(const bf16x8*)&vb[(size_t)(mt * 16 + q15) * T + s0 + 32 + g * 8];
      o[mt] = MFMA16(vf1, pf1, o[mt]);
    }
  }

  // fp32 epilogue: out[q][h], lane (q15,g) holds h = mt*16 + g*4 + r
  const float inv = 1.0f / lrun;
#pragma unroll
  for (int mt = 0; mt < 8; ++mt) {
    f32x4 pk;
#pragma unroll
    for (int r = 0; r < 4; ++r) pk[r] = o[mt][r] * inv;
    *(f32x4*)&ob[(size_t)(q0 + q15) * H + mt * 16 + g * 4] = pk;
  }
}

// ---------------------------------------------------------------------------
extern "C" void kernel_launch(void* const* d_in, const int* in_sizes, int n_in,
                              void* d_out, int out_size, void* d_ws, size_t ws_size,
                              hipStream_t stream) {
  const float* x  = (const float*)d_in[0];   // fp32 inputs per reference
  const float* Wq = (const float*)d_in[1];
  const float* Wk = (const float*)d_in[2];
  const float* Wv = (const float*)d_in[3];
  float* out = (float*)d_out;                // fp32 output (reference returns f32)

  bf16* wth = (bf16*)d_ws;                   // 3*H*C
  bf16* wtl = wth + (size_t)3 * H * C;       // 3*H*C
  bf16* qh  = wtl + (size_t)3 * H * C;       // M*H each below
  bf16* ql  = qh + (size_t)M * H;
  bf16* kh  = ql + (size_t)M * H;
  bf16* kl  = kh + (size_t)M * H;
  bf16* vt  = kl + (size_t)M * H;            // [B][H][T]

  kwt<<<dim3(C / 32, H / 32, 3), 256, 0, stream>>>(Wq, Wk, Wv, wth, wtl);
  proj_kernel<<<dim3(M / 64, 3), 256, 0, stream>>>(x, wth, wtl, qh, ql, kh, kl, vt);
  attn_kernel<<<256, 256, 0, stream>>>(qh, ql, kh, kl, vt, out);
}

// Round 4
// 202.371 us; speedup vs baseline: 1.1866x; 1.1866x over previous
//
#include <hip/hip_runtime.h>

typedef __bf16 bf16;
typedef __bf16 bf16x4 __attribute__((ext_vector_type(4)));
typedef __bf16 bf16x8 __attribute__((ext_vector_type(8)));
typedef float  f32x4  __attribute__((ext_vector_type(4)));

#define MFMA16(a, b, c) __builtin_amdgcn_mfma_f32_16x16x32_bf16((a), (b), (c), 0, 0, 0)

static constexpr int Bn = 8, T = 2048, C = 1024, H = 128;
static constexpr int M = Bn * T; // 16384

// ---------------------------------------------------------------------------
// Kernel 0: transpose + hi/lo split  W[C][H] fp32 -> wt_hi/wt_lo [3][H][C] bf16
// ---------------------------------------------------------------------------
__global__ __launch_bounds__(256) void kwt(const float* __restrict__ Wq,
                                           const float* __restrict__ Wk,
                                           const float* __restrict__ Wv,
                                           bf16* __restrict__ wth,
                                           bf16* __restrict__ wtl) {
  __shared__ float tl[32][33];
  const int w = blockIdx.z;
  const float* src = (w == 0) ? Wq : (w == 1) ? Wk : Wv;
  bf16* dh = wth + (size_t)w * H * C;
  bf16* dl = wtl + (size_t)w * H * C;
  const int k0 = blockIdx.x * 32, n0 = blockIdx.y * 32;
  const int tx = threadIdx.x & 31, ty = threadIdx.x >> 5; // 32 x 8
  for (int i = ty; i < 32; i += 8) tl[i][tx] = src[(size_t)(k0 + i) * H + n0 + tx];
  __syncthreads();
  for (int i = ty; i < 32; i += 8) {
    float v = tl[tx][i];
    bf16 h = (bf16)v;
    bf16 l = (bf16)(v - (float)h);
    dh[(size_t)(n0 + i) * C + k0 + tx] = h;
    dl[(size_t)(n0 + i) * C + k0 + tx] = l;
  }
}

// ---------------------------------------------------------------------------
// Kernel 1: QKV projection, split-bf16 3-term (hh + lh + hl) for accuracy.
// grid (M/64, 3).  256 thr = 4 waves (2x2).  Tile 64m x 128n, BK=64.
// ---------------------------------------------------------------------------
__global__ __launch_bounds__(256) void proj_kernel(const float* __restrict__ x,
                                                   const bf16* __restrict__ wth,
                                                   const bf16* __restrict__ wtl,
                                                   bf16* __restrict__ qh, bf16* __restrict__ ql,
                                                   bf16* __restrict__ kh, bf16* __restrict__ kl,
                                                   bf16* __restrict__ vt) {
  __shared__ __align__(16) bf16 Ah[64 * 72], Al[64 * 72];    // [m][k] padded
  __shared__ __align__(16) bf16 Bh[128 * 72], Bl[128 * 72];  // [n][k] padded
  const int tid = threadIdx.x;
  const int lane = tid & 63, g = lane >> 4, r16 = lane & 15;
  const int wave = tid >> 6, wr = wave >> 1, wc = wave & 1;
  const int m0 = blockIdx.x * 64;
  const int which = blockIdx.y;
  const bf16* wh = wth + (size_t)which * H * C;
  const bf16* wl = wtl + (size_t)which * H * C;

  int am[4], ak[4], bn[4], bk[4];
#pragma unroll
  for (int it = 0; it < 4; ++it) {
    int c = it * 256 + tid;
    am[it] = c >> 4; ak[it] = (c & 15) << 2;
    bn[it] = c >> 3; bk[it] = (c & 7) << 3;
  }

  f32x4 ra[4]; bf16x8 rbh[4], rbl[4];
#pragma unroll
  for (int it = 0; it < 4; ++it) {
    ra[it]  = *(const f32x4*)&x[(size_t)(m0 + am[it]) * C + ak[it]];
    rbh[it] = *(const bf16x8*)&wh[(size_t)bn[it] * C + bk[it]];
    rbl[it] = *(const bf16x8*)&wl[(size_t)bn[it] * C + bk[it]];
  }

  f32x4 acc[2][4] = {};

  for (int k0 = 0; k0 < C; k0 += 64) {
    __syncthreads();
#pragma unroll
    for (int it = 0; it < 4; ++it) {
      bf16x4 hv, lv;
#pragma unroll
      for (int j = 0; j < 4; ++j) {
        float v = ra[it][j];
        bf16 h = (bf16)v;
        hv[j] = h;
        lv[j] = (bf16)(v - (float)h);
      }
      *(bf16x4*)&Ah[am[it] * 72 + ak[it]] = hv;
      *(bf16x4*)&Al[am[it] * 72 + ak[it]] = lv;
      *(bf16x8*)&Bh[bn[it] * 72 + bk[it]] = rbh[it];
      *(bf16x8*)&Bl[bn[it] * 72 + bk[it]] = rbl[it];
    }
    if (k0 + 64 < C) {
      const int kn = k0 + 64;
#pragma unroll
      for (int it = 0; it < 4; ++it) {
        ra[it]  = *(const f32x4*)&x[(size_t)(m0 + am[it]) * C + kn + ak[it]];
        rbh[it] = *(const bf16x8*)&wh[(size_t)bn[it] * C + kn + bk[it]];
        rbl[it] = *(const bf16x8*)&wl[(size_t)bn[it] * C + kn + bk[it]];
      }
    }
    __syncthreads();
#pragma unroll
    for (int kb = 0; kb < 2; ++kb) {
      bf16x8 afh[2], afl[2], bfh[4], bfl[4];
#pragma unroll
      for (int mt = 0; mt < 2; ++mt) {
        const int ro = (wr * 32 + mt * 16 + r16) * 72 + kb * 32 + g * 8;
        afh[mt] = *(const bf16x8*)&Ah[ro];
        afl[mt] = *(const bf16x8*)&Al[ro];
      }
#pragma unroll
      for (int nt = 0; nt < 4; ++nt) {
        const int ro = (wc * 64 + nt * 16 + r16) * 72 + kb * 32 + g * 8;
        bfh[nt] = *(const bf16x8*)&Bh[ro];
        bfl[nt] = *(const bf16x8*)&Bl[ro];
      }
#pragma unroll
      for (int mt = 0; mt < 2; ++mt)
#pragma unroll
        for (int nt = 0; nt < 4; ++nt) {
          acc[mt][nt] = MFMA16(afh[mt], bfh[nt], acc[mt][nt]);
          acc[mt][nt] = MFMA16(afl[mt], bfh[nt], acc[mt][nt]);
          acc[mt][nt] = MFMA16(afh[mt], bfl[nt], acc[mt][nt]);
        }
    }
  }

  if (which < 2) {
    bf16* dh = which ? kh : qh;
    bf16* dl = which ? kl : ql;
#pragma unroll
    for (int mt = 0; mt < 2; ++mt)
#pragma unroll
      for (int nt = 0; nt < 4; ++nt) {
        const int mb = m0 + wr * 32 + mt * 16 + g * 4;
        const int col = wc * 64 + nt * 16 + r16;
#pragma unroll
        for (int r = 0; r < 4; ++r) {
          float v = acc[mt][nt][r];
          bf16 h = (bf16)v;
          dh[(size_t)(mb + r) * H + col] = h;
          dl[(size_t)(mb + r) * H + col] = (bf16)(v - (float)h);
        }
      }
  } else {
    const int b = m0 >> 11;
    const int tb0 = m0 & 2047;
    bf16* vbase = vt + (size_t)b * H * T;
#pragma unroll
    for (int mt = 0; mt < 2; ++mt)
#pragma unroll
      for (int nt = 0; nt < 4; ++nt) {
        const int tib = tb0 + wr * 32 + mt * 16 + g * 4;
        const int h = wc * 64 + nt * 16 + r16;
        bf16x4 pk;
#pragma unroll
        for (int r = 0; r < 4; ++r) pk[r] = (bf16)acc[mt][nt][r];
        *(bf16x4*)&vbase[(size_t)h * T + tib] = pk;
      }
  }
}

// ---------------------------------------------------------------------------
// Kernel 2: causal flash attention with intra-block KV-split.
// 1024 blocks = one per (batch, 16-q-row) task, heavy tasks first.
// 4 waves/block each take s-tiles j = wave, wave+4, ... with private
// online-softmax state (m, l, o); two-round pairwise LDS combine at the end.
// Swapped QK^T (mfma(K,Q)): lane owns one q row -> shuffle softmax.
// PV: A = V^T [b][h][t], B = P^T via per-wave LDS round-trip -> out^T.
// ---------------------------------------------------------------------------
__global__ __launch_bounds__(256) void attn_kernel(const bf16* __restrict__ qhp,
                                                   const bf16* __restrict__ qlp,
                                                   const bf16* __restrict__ khp,
                                                   const bf16* __restrict__ klp,
                                                   const bf16* __restrict__ vp,
                                                   float* __restrict__ out) {
  // Pl (loop phase): bf16 [4][16][72] = 9216 B.  Osum (combine): f32 [2][16][132] = 16896 B.
  __shared__ __align__(16) char smem[16896];
  bf16 (*Pl)[16][72] = (bf16(*)[16][72])smem;
  float (*Osum)[16][132] = (float(*)[16][132])smem;
  __shared__ float Ml[4][16], Ll[4][16];

  const int tid = threadIdx.x, lane = tid & 63, wave = tid >> 6;
  const int g = lane >> 4, q15 = lane & 15;
  const int bb = blockIdx.x;
  const int batch = bb >> 7, qg = 127 - (bb & 127); // heavy tasks dispatch first
  const int q0 = qg * 16;
  const bf16* qbh = qhp + (size_t)batch * T * H;
  const bf16* qbl = qlp + (size_t)batch * T * H;
  const bf16* kbh = khp + (size_t)batch * T * H;
  const bf16* kbl = klp + (size_t)batch * T * H;
  const bf16* vb  = vp  + (size_t)batch * H * T;
  float* ob = out + (size_t)batch * T * H;

  // Q B-frags, hoisted: col = q (lane&15), k = h contiguous
  bf16x8 qfh[4], qfl[4];
#pragma unroll
  for (int k4 = 0; k4 < 4; ++k4) {
    qfh[k4] = *(const bf16x8*)&qbh[(size_t)(q0 + q15) * H + k4 * 32 + g * 8];
    qfl[k4] = *(const bf16x8*)&qbl[(size_t)(q0 + q15) * H + k4 * 32 + g * 8];
  }

  f32x4 o[8] = {};
  float mrun = -1e30f, lrun = 0.f;
  const int ntiles = (qg >> 2) + 1;

  for (int j = wave; j < ntiles; j += 4) {
    const int s0 = j * 64;
    const bool lastt = (j == ntiles - 1);
    // S^T[s][q]: A = K rows (row = s, k = h), B = Q.  3-term split product.
    f32x4 sacc[4] = {};
#pragma unroll
    for (int mt = 0; mt < 4; ++mt) {
#pragma unroll
      for (int k4 = 0; k4 < 4; ++k4) {
        const size_t ro = (size_t)(s0 + mt * 16 + q15) * H + k4 * 32 + g * 8;
        bf16x8 kfh = *(const bf16x8*)&kbh[ro];
        bf16x8 kfl = *(const bf16x8*)&kbl[ro];
        sacc[mt] = MFMA16(kfh, qfh[k4], sacc[mt]);
        sacc[mt] = MFMA16(kfl, qfh[k4], sacc[mt]);
        sacc[mt] = MFMA16(kfh, qfl[k4], sacc[mt]);
      }
    }
    if (lastt) {
#pragma unroll
      for (int mt = 0; mt < 4; ++mt)
#pragma unroll
        for (int r = 0; r < 4; ++r)
          if (s0 + mt * 16 + g * 4 + r > q0 + q15) sacc[mt][r] = -1e30f;
    }
    // online softmax: lane holds 16 s-values of ONE q row (shfl 16/32 reduce)
    float tmax = -1e30f;
#pragma unroll
    for (int mt = 0; mt < 4; ++mt)
#pragma unroll
      for (int r = 0; r < 4; ++r) tmax = fmaxf(tmax, sacc[mt][r]);
    tmax = fmaxf(tmax, __shfl_xor(tmax, 16));
    tmax = fmaxf(tmax, __shfl_xor(tmax, 32));
    const float mnew = fmaxf(mrun, tmax);
    const float alpha = __expf(mrun - mnew);
    float lt = 0.f;
#pragma unroll
    for (int mt = 0; mt < 4; ++mt) {
      bf16x4 pk;
#pragma unroll
      for (int r = 0; r < 4; ++r) {
        const float p = __expf(sacc[mt][r] - mnew);
        lt += p;
        pk[r] = (bf16)p;
      }
      *(bf16x4*)&Pl[wave][q15][mt * 16 + g * 4] = pk; // own-wave slice, no barrier
    }
    lt += __shfl_xor(lt, 16);
    lt += __shfl_xor(lt, 32);
    lrun = lrun * alpha + lt;
    mrun = mnew;
#pragma unroll
    for (int i = 0; i < 8; ++i) o[i] *= alpha;
    // P^T B-frags: col = q, k = s contiguous
    const bf16x8 pf0 = *(const bf16x8*)&Pl[wave][q15][g * 8];
    const bf16x8 pf1 = *(const bf16x8*)&Pl[wave][q15][32 + g * 8];
    // out^T += V^T * P^T  (A = V^T rows: row = h, k = s contiguous)
#pragma unroll
    for (int mt = 0; mt < 8; ++mt) {
      const bf16x8 vf0 = *(const bf16x8*)&vb[(size_t)(mt * 16 + q15) * T + s0 + g * 8];
      o[mt] = MFMA16(vf0, pf0, o[mt]);
      const bf16x8 vf1 = *(const bf16x8*)&vb[(size_t)(mt * 16 + q15) * T + s0 + 32 + g * 8];
      o[mt] = MFMA16(vf1, pf1, o[mt]);
    }
  }

  // ---- cross-wave combine (m/l rescale, two-round pairwise o-sum) ----
  if (lane < 16) { Ml[wave][lane] = mrun; Ll[wave][lane] = lrun; }
  __syncthreads();
  const float m0v = Ml[0][q15], m1v = Ml[1][q15], m2v = Ml[2][q15], m3v = Ml[3][q15];
  const float mg = fmaxf(fmaxf(m0v, m1v), fmaxf(m2v, m3v));
  const float ls = Ll[0][q15] * __expf(m0v - mg) + Ll[1][q15] * __expf(m1v - mg)
                 + Ll[2][q15] * __expf(m2v - mg) + Ll[3][q15] * __expf(m3v - mg);
  const float sc = __expf(mrun - mg);
#pragma unroll
  for (int i = 0; i < 8; ++i) o[i] *= sc;
  __syncthreads(); // Pl phase done before Osum overwrite
  // round 1: waves 1,3 publish; waves 0,2 accumulate
  if (wave & 1) {
#pragma unroll
    for (int mt = 0; mt < 8; ++mt)
      *(f32x4*)&Osum[wave >> 1][q15][mt * 16 + g * 4] = o[mt];
  }
  __syncthreads();
  if (!(wave & 1)) {
#pragma unroll
    for (int mt = 0; mt < 8; ++mt)
      o[mt] += *(const f32x4*)&Osum[wave >> 1][q15][mt * 16 + g * 4];
  }
  __syncthreads();
  // round 2: wave 2 publishes; wave 0 finishes
  if (wave == 2) {
#pragma unroll
    for (int mt = 0; mt < 8; ++mt)
      *(f32x4*)&Osum[0][q15][mt * 16 + g * 4] = o[mt];
  }
  __syncthreads();
  if (wave == 0) {
    const float inv = 1.0f / ls;
#pragma unroll
    for (int mt = 0; mt < 8; ++mt) {
      f32x4 pk;
#pragma unroll
      for (int r = 0; r < 4; ++r)
        pk[r] = (o[mt][r] + Osum[0][q15][mt * 16 + g * 4 + r]) * inv;
      *(f32x4*)&ob[(size_t)(q0 + q15) * H + mt * 16 + g * 4] = pk;
    }
  }
}

// ---------------------------------------------------------------------------
extern "C" void kernel_launch(void* const* d_in, const int* in_sizes, int n_in,
                              void* d_out, int out_size, void* d_ws, size_t ws_size,
                              hipStream_t stream) {
  const float* x  = (const float*)d_in[0];   // fp32 inputs per reference
  const float* Wq = (const float*)d_in[1];
  const float* Wk = (const float*)d_in[2];
  const float* Wv = (const float*)d_in[3];
  float* out = (float*)d_out;                // fp32 output

  bf16* wth = (bf16*)d_ws;                   // 3*H*C
  bf16* wtl = wth + (size_t)3 * H * C;       // 3*H*C
  bf16* qh  = wtl + (size_t)3 * H * C;       // M*H each below
  bf16* ql  = qh + (size_t)M * H;
  bf16* kh  = ql + (size_t)M * H;
  bf16* kl  = kh + (size_t)M * H;
  bf16* vt  = kl + (size_t)M * H;            // [B][H][T]

  kwt<<<dim3(C / 32, H / 32, 3), 256, 0, stream>>>(Wq, Wk, Wv, wth, wtl);
  proj_kernel<<<dim3(M / 64, 3), 256, 0, stream>>>(x, wth, wtl, qh, ql, kh, kl, vt);
  attn_kernel<<<1024, 256, 0, stream>>>(qh, ql, kh, kl, vt, out);
}

// Round 5
// 122.067 us; speedup vs baseline: 1.9673x; 1.6579x over previous
//
#include <hip/hip_runtime.h>

typedef __bf16 bf16;
typedef __bf16 bf16x4 __attribute__((ext_vector_type(4)));
typedef __bf16 bf16x8 __attribute__((ext_vector_type(8)));
typedef float  f32x4  __attribute__((ext_vector_type(4)));

#define MFMA16(a, b, c) __builtin_amdgcn_mfma_f32_16x16x32_bf16((a), (b), (c), 0, 0, 0)

static constexpr int Bn = 8, T = 2048, C = 1024, H = 128;
static constexpr int M = Bn * T; // 16384

// ---------------------------------------------------------------------------
// Kernel 0: transpose + hi/lo split  W[C][H] fp32 -> wt_hi/wt_lo [3][H][C] bf16
// ---------------------------------------------------------------------------
__global__ __launch_bounds__(256) void kwt(const float* __restrict__ Wq,
                                           const float* __restrict__ Wk,
                                           const float* __restrict__ Wv,
                                           bf16* __restrict__ wth,
                                           bf16* __restrict__ wtl) {
  __shared__ float tl[32][33];
  const int w = blockIdx.z;
  const float* src = (w == 0) ? Wq : (w == 1) ? Wk : Wv;
  bf16* dh = wth + (size_t)w * H * C;
  bf16* dl = wtl + (size_t)w * H * C;
  const int k0 = blockIdx.x * 32, n0 = blockIdx.y * 32;
  const int tx = threadIdx.x & 31, ty = threadIdx.x >> 5; // 32 x 8
  for (int i = ty; i < 32; i += 8) tl[i][tx] = src[(size_t)(k0 + i) * H + n0 + tx];
  __syncthreads();
  for (int i = ty; i < 32; i += 8) {
    float v = tl[tx][i];
    bf16 h = (bf16)v;
    bf16 l = (bf16)(v - (float)h);
    dh[(size_t)(n0 + i) * C + k0 + tx] = h;
    dl[(size_t)(n0 + i) * C + k0 + tx] = l;
  }
}

// ---------------------------------------------------------------------------
// Kernel 1: QKV projection, split-bf16 3-term (hh + lh + hl) for q,k accuracy;
// V (which==2) uses hh only (rounded to bf16 anyway).
// grid (M/64, 3).  256 thr = 4 waves (2x2).  Tile 64m x 128n, BK=64.
// ---------------------------------------------------------------------------
__global__ __launch_bounds__(256) void proj_kernel(const float* __restrict__ x,
                                                   const bf16* __restrict__ wth,
                                                   const bf16* __restrict__ wtl,
                                                   bf16* __restrict__ qh, bf16* __restrict__ ql,
                                                   bf16* __restrict__ kh, bf16* __restrict__ kl,
                                                   bf16* __restrict__ vt) {
  __shared__ __align__(16) bf16 Ah[64 * 72], Al[64 * 72];    // [m][k] padded
  __shared__ __align__(16) bf16 Bh[128 * 72], Bl[128 * 72];  // [n][k] padded
  const int tid = threadIdx.x;
  const int lane = tid & 63, g = lane >> 4, r16 = lane & 15;
  const int wave = tid >> 6, wr = wave >> 1, wc = wave & 1;
  const int m0 = blockIdx.x * 64;
  const int which = blockIdx.y;
  const bool split = (which < 2);
  const bf16* wh = wth + (size_t)which * H * C;
  const bf16* wl = wtl + (size_t)which * H * C;

  int am[4], ak[4], bn[4], bk[4];
#pragma unroll
  for (int it = 0; it < 4; ++it) {
    int c = it * 256 + tid;
    am[it] = c >> 4; ak[it] = (c & 15) << 2;
    bn[it] = c >> 3; bk[it] = (c & 7) << 3;
  }

  f32x4 ra[4]; bf16x8 rbh[4], rbl[4];
#pragma unroll
  for (int it = 0; it < 4; ++it) {
    ra[it]  = *(const f32x4*)&x[(size_t)(m0 + am[it]) * C + ak[it]];
    rbh[it] = *(const bf16x8*)&wh[(size_t)bn[it] * C + bk[it]];
    if (split) rbl[it] = *(const bf16x8*)&wl[(size_t)bn[it] * C + bk[it]];
  }

  f32x4 acc[2][4] = {};

  for (int k0 = 0; k0 < C; k0 += 64) {
    __syncthreads();
#pragma unroll
    for (int it = 0; it < 4; ++it) {
      bf16x4 hv, lv;
#pragma unroll
      for (int j = 0; j < 4; ++j) {
        float v = ra[it][j];
        bf16 h = (bf16)v;
        hv[j] = h;
        lv[j] = (bf16)(v - (float)h);
      }
      *(bf16x4*)&Ah[am[it] * 72 + ak[it]] = hv;
      *(bf16x8*)&Bh[bn[it] * 72 + bk[it]] = rbh[it];
      if (split) {
        *(bf16x4*)&Al[am[it] * 72 + ak[it]] = lv;
        *(bf16x8*)&Bl[bn[it] * 72 + bk[it]] = rbl[it];
      }
    }
    if (k0 + 64 < C) {
      const int kn = k0 + 64;
#pragma unroll
      for (int it = 0; it < 4; ++it) {
        ra[it]  = *(const f32x4*)&x[(size_t)(m0 + am[it]) * C + kn + ak[it]];
        rbh[it] = *(const bf16x8*)&wh[(size_t)bn[it] * C + kn + bk[it]];
        if (split) rbl[it] = *(const bf16x8*)&wl[(size_t)bn[it] * C + kn + bk[it]];
      }
    }
    __syncthreads();
#pragma unroll
    for (int kb = 0; kb < 2; ++kb) {
      bf16x8 afh[2], afl[2], bfh[4], bfl[4];
#pragma unroll
      for (int mt = 0; mt < 2; ++mt) {
        const int ro = (wr * 32 + mt * 16 + r16) * 72 + kb * 32 + g * 8;
        afh[mt] = *(const bf16x8*)&Ah[ro];
        if (split) afl[mt] = *(const bf16x8*)&Al[ro];
      }
#pragma unroll
      for (int nt = 0; nt < 4; ++nt) {
        const int ro = (wc * 64 + nt * 16 + r16) * 72 + kb * 32 + g * 8;
        bfh[nt] = *(const bf16x8*)&Bh[ro];
        if (split) bfl[nt] = *(const bf16x8*)&Bl[ro];
      }
#pragma unroll
      for (int mt = 0; mt < 2; ++mt)
#pragma unroll
        for (int nt = 0; nt < 4; ++nt) {
          acc[mt][nt] = MFMA16(afh[mt], bfh[nt], acc[mt][nt]);
          if (split) {
            acc[mt][nt] = MFMA16(afl[mt], bfh[nt], acc[mt][nt]);
            acc[mt][nt] = MFMA16(afh[mt], bfl[nt], acc[mt][nt]);
          }
        }
    }
  }

  if (which < 2) {
    bf16* dh = which ? kh : qh;
    bf16* dl = which ? kl : ql;
#pragma unroll
    for (int mt = 0; mt < 2; ++mt)
#pragma unroll
      for (int nt = 0; nt < 4; ++nt) {
        const int mb = m0 + wr * 32 + mt * 16 + g * 4;
        const int col = wc * 64 + nt * 16 + r16;
#pragma unroll
        for (int r = 0; r < 4; ++r) {
          float v = acc[mt][nt][r];
          bf16 h = (bf16)v;
          dh[(size_t)(mb + r) * H + col] = h;
          dl[(size_t)(mb + r) * H + col] = (bf16)(v - (float)h);
        }
      }
  } else {
    const int b = m0 >> 11;
    const int tb0 = m0 & 2047;
    bf16* vbase = vt + (size_t)b * H * T;
#pragma unroll
    for (int mt = 0; mt < 2; ++mt)
#pragma unroll
      for (int nt = 0; nt < 4; ++nt) {
        const int tib = tb0 + wr * 32 + mt * 16 + g * 4;
        const int h = wc * 64 + nt * 16 + r16;
        bf16x4 pk;
#pragma unroll
        for (int r = 0; r < 4; ++r) pk[r] = (bf16)acc[mt][nt][r];
        *(bf16x4*)&vbase[(size_t)h * T + tib] = pk;
      }
  }
}

// ---------------------------------------------------------------------------
// Kernel 2: causal flash attention, LDS-shared K/V tiles.
// 256 blocks = (batch = bb&7 -> XCD-local L2, qt = 31-(bb>>3), 64 q rows).
// 4 waves x 16 q rows each; per s-tile (64 s): K hi/lo + V^T staged in LDS
// (reg-staged, T14 async: loads issued at tile start, ds_write after barrier).
// XOR chunk-swizzle (chunk ^= row&7) on K (256B rows) and V (128B rows)
// makes ds_read_b128 conflict-free.  Single buffer, 2 barriers per tile.
// ---------------------------------------------------------------------------
__global__ __launch_bounds__(256, 2) void attn_kernel(const bf16* __restrict__ qhp,
                                                      const bf16* __restrict__ qlp,
                                                      const bf16* __restrict__ khp,
                                                      const bf16* __restrict__ klp,
                                                      const bf16* __restrict__ vp,
                                                      float* __restrict__ out) {
  __shared__ __align__(16) bf16 KH[64 * 128];   // [s][h], chunk-swizzled
  __shared__ __align__(16) bf16 KL[64 * 128];
  __shared__ __align__(16) bf16 VS[128 * 64];   // [h][s], chunk-swizzled
  __shared__ __align__(16) bf16 Pl[4][16][72];  // per-wave P [q][s], padded

  const int tid = threadIdx.x, lane = tid & 63, wave = tid >> 6;
  const int g = lane >> 4, q15 = lane & 15;
  const int x7 = q15 & 7;
  const int bb = blockIdx.x;
  const int batch = bb & 7;            // block->XCD is round-robin: batch pins XCD
  const int qt = 31 - (bb >> 3);       // heavy q-tiles dispatch first
  const int q0 = qt * 64;
  const int qrow = q0 + wave * 16 + q15;

  const bf16* qbh = qhp + (size_t)batch * T * H;
  const bf16* qbl = qlp + (size_t)batch * T * H;
  const bf16* kbh = khp + (size_t)batch * T * H;
  const bf16* kbl = klp + (size_t)batch * T * H;
  const bf16* vb  = vp  + (size_t)batch * H * T;
  float* ob = out + (size_t)batch * T * H;

  // staging geometry: 16 units of 1KB per array; wave stages units wave*4+i.
  // K unit u: c = u*64+lane; row r = u*4+(lane>>4); phys chunk p = lane&15;
  //   logical chunk = p ^ (r&7) -> source offset r*H + q*8.  LDS write linear.
  // V unit u: c = u*64+lane; row h = u*8+(lane>>3); p = lane&7; q = p^(h&7).
  int koff[4], voff[4];
#pragma unroll
  for (int i = 0; i < 4; ++i) {
    const int u = wave * 4 + i;
    const int r = u * 4 + (lane >> 4);
    const int qk = (lane & 15) ^ (r & 7);
    koff[i] = r * H + qk * 8;
    const int h = u * 8 + (lane >> 3);
    const int qv = (lane & 7) ^ (h & 7);
    voff[i] = h * T + qv * 8;
  }
  const int lb = wave * 4 * 512 + lane * 8;   // LDS elem base for unit i: + i*512

  bf16x8 rkh[4], rkl[4], rv[4];

#define LOADT(S0)                                                     \
  _Pragma("unroll")                                                   \
  for (int i = 0; i < 4; ++i) {                                       \
    rkh[i] = *(const bf16x8*)&kbh[(size_t)(S0) * H + koff[i]];        \
    rkl[i] = *(const bf16x8*)&kbl[(size_t)(S0) * H + koff[i]];        \
    rv[i]  = *(const bf16x8*)&vb[(size_t)(S0) + voff[i]];             \
  }
#define WRITET()                                                      \
  _Pragma("unroll")                                                   \
  for (int i = 0; i < 4; ++i) {                                       \
    *(bf16x8*)&KH[lb + i * 512] = rkh[i];                             \
    *(bf16x8*)&KL[lb + i * 512] = rkl[i];                             \
    *(bf16x8*)&VS[lb + i * 512] = rv[i];                              \
  }

  // Q B-frags, hoisted: col = q (lane&15), k = h contiguous
  bf16x8 qfh[4], qfl[4];
#pragma unroll
  for (int k4 = 0; k4 < 4; ++k4) {
    qfh[k4] = *(const bf16x8*)&qbh[(size_t)qrow * H + k4 * 32 + g * 8];
    qfl[k4] = *(const bf16x8*)&qbl[(size_t)qrow * H + k4 * 32 + g * 8];
  }

  f32x4 o[8] = {};
  float mrun = -1e30f, lrun = 0.f;
  const int ntiles = qt + 1;

  LOADT(0);
  WRITET();
  __syncthreads();

  for (int j = 0; j < ntiles; ++j) {
    const int s0 = j * 64;
    if (j + 1 < ntiles) LOADT(s0 + 64);   // async prefetch; lands in regs

    // S^T[s][q]: A = K rows from LDS (swizzled), B = Q.  3-term split.
    f32x4 sacc[4] = {};
#pragma unroll
    for (int mt = 0; mt < 4; ++mt) {
      const int row = mt * 16 + q15;
#pragma unroll
      for (int k4 = 0; k4 < 4; ++k4) {
        const int pch = (k4 * 4 + g) ^ x7;
        const bf16x8 kfh = *(const bf16x8*)&KH[row * 128 + pch * 8];
        const bf16x8 kfl = *(const bf16x8*)&KL[row * 128 + pch * 8];
        sacc[mt] = MFMA16(kfh, qfh[k4], sacc[mt]);
        sacc[mt] = MFMA16(kfl, qfh[k4], sacc[mt]);
        sacc[mt] = MFMA16(kfh, qfl[k4], sacc[mt]);
      }
    }
    if (j == ntiles - 1) {
#pragma unroll
      for (int mt = 0; mt < 4; ++mt)
#pragma unroll
        for (int r = 0; r < 4; ++r)
          if (s0 + mt * 16 + g * 4 + r > qrow) sacc[mt][r] = -1e30f;
    }
    // online softmax: lane owns one q row (shfl 16/32 reduce)
    float tmax = -1e30f;
#pragma unroll
    for (int mt = 0; mt < 4; ++mt)
#pragma unroll
      for (int r = 0; r < 4; ++r) tmax = fmaxf(tmax, sacc[mt][r]);
    tmax = fmaxf(tmax, __shfl_xor(tmax, 16));
    tmax = fmaxf(tmax, __shfl_xor(tmax, 32));
    const float mnew = fmaxf(mrun, tmax);
    const float alpha = __expf(mrun - mnew);
    float lt = 0.f;
#pragma unroll
    for (int mt = 0; mt < 4; ++mt) {
      bf16x4 pk;
#pragma unroll
      for (int r = 0; r < 4; ++r) {
        const float p = __expf(sacc[mt][r] - mnew);
        lt += p;
        pk[r] = (bf16)p;
      }
      *(bf16x4*)&Pl[wave][q15][mt * 16 + g * 4] = pk; // own-wave slice
    }
    lt += __shfl_xor(lt, 16);
    lt += __shfl_xor(lt, 32);
    lrun = lrun * alpha + lt;
    mrun = mnew;
#pragma unroll
    for (int i = 0; i < 8; ++i) o[i] *= alpha;
    const bf16x8 pf0 = *(const bf16x8*)&Pl[wave][q15][g * 8];
    const bf16x8 pf1 = *(const bf16x8*)&Pl[wave][q15][32 + g * 8];
    // out^T += V^T * P^T  (A = V rows [h][s] from LDS, swizzled)
#pragma unroll
    for (int mt = 0; mt < 8; ++mt) {
      const int h = mt * 16 + q15;
      const int p0 = g ^ x7, p1 = (4 + g) ^ x7;
      const bf16x8 vf0 = *(const bf16x8*)&VS[h * 64 + p0 * 8];
      o[mt] = MFMA16(vf0, pf0, o[mt]);
      const bf16x8 vf1 = *(const bf16x8*)&VS[h * 64 + p1 * 8];
      o[mt] = MFMA16(vf1, pf1, o[mt]);
    }

    if (j + 1 < ntiles) {
      __syncthreads();   // everyone done reading current tile
      WRITET();          // commit prefetched tile (vmcnt drained by use)
      __syncthreads();   // tile ready
    }
  }

  const float inv = 1.0f / lrun;
#pragma unroll
  for (int mt = 0; mt < 8; ++mt) {
    f32x4 pk;
#pragma unroll
    for (int r = 0; r < 4; ++r) pk[r] = o[mt][r] * inv;
    *(f32x4*)&ob[(size_t)qrow * H + mt * 16 + g * 4] = pk;
  }
#undef LOADT
#undef WRITET
}

// ---------------------------------------------------------------------------
extern "C" void kernel_launch(void* const* d_in, const int* in_sizes, int n_in,
                              void* d_out, int out_size, void* d_ws, size_t ws_size,
                              hipStream_t stream) {
  const float* x  = (const float*)d_in[0];   // fp32 inputs per reference
  const float* Wq = (const float*)d_in[1];
  const float* Wk = (const float*)d_in[2];
  const float* Wv = (const float*)d_in[3];
  float* out = (float*)d_out;                // fp32 output

  bf16* wth = (bf16*)d_ws;                   // 3*H*C
  bf16* wtl = wth + (size_t)3 * H * C;       // 3*H*C
  bf16* qh  = wtl + (size_t)3 * H * C;       // M*H each below
  bf16* ql  = qh + (size_t)M * H;
  bf16* kh  = ql + (size_t)M * H;
  bf16* kl  = kh + (size_t)M * H;
  bf16* vt  = kl + (size_t)M * H;            // [B][H][T]

  kwt<<<dim3(C / 32, H / 32, 3), 256, 0, stream>>>(Wq, Wk, Wv, wth, wtl);
  proj_kernel<<<dim3(M / 64, 3), 256, 0, stream>>>(x, wth, wtl, qh, ql, kh, kl, vt);
  attn_kernel<<<256, 256, 0, stream>>>(qh, ql, kh, kl, vt, out);
}